// Round 22
// baseline (71557.440 us; speedup 1.0000x reference)
//
#include <hip/hip_runtime.h>

// R22: R13's audited brute-force implementation with FLOAT32 output.
// Root cause of 21 rounds of failure: reference output dtype is f32; all
// prior rounds wrote u16/bf16 into the f32 buffer (pairs read as garbage
// floats; single-u16 stamps read as denormals ~ 0).

constexpr int T_ = 256, B_ = 128, H_ = 512;

__device__ __forceinline__ float sig_(float x) { return 1.f / (1.f + expf(-x)); }

__device__ __forceinline__ float bsum(float v, float* red) {
  const int tid = threadIdx.x;
  red[tid] = v;
  __syncthreads();
  for (int s = 128; s > 0; s >>= 1) {
    if (tid < s) red[tid] += red[tid + s];
    __syncthreads();
  }
  float r = red[0];
  __syncthreads();
  return r;
}

__global__ void fill6f(float* __restrict__ o, long long n) {
  for (long long i = (long long)blockIdx.x * 256 + threadIdx.x; i < n;
       i += (long long)gridDim.x * 256)
    o[i] = 6.0f;  // guard signal
}

// ---- k1: one block per batch row b ----
__global__ __launch_bounds__(256) void f_k1(
    const float* __restrict__ x,    // [T,B,512]
    const float* __restrict__ W,    // [2048,1024]
    const float* __restrict__ bb,   // [2048]
    const float* __restrict__ Wm,   // [512,512]
    const float* __restrict__ bm,   // [512]
    const float* __restrict__ lg,   // [4,512]
    const float* __restrict__ lb,   // [4,512]
    const float* __restrict__ hmod, // [128,512]  h_mod(t-1) carry
    float* __restrict__ cbuf,       // [128,512]  cx state
    float* __restrict__ hbuf,       // [128,512]  un-modulated h(t)
    float* __restrict__ imb,        // [128,512]  im(t)
    float* __restrict__ nab,        // [128]
    float* __restrict__ gcob,       // [128]
    int t) {
  __shared__ float xs[512];
  __shared__ float hs[512];
  __shared__ float gt[2048];
  __shared__ float ac[2048];
  __shared__ float red[256];
  const int b = blockIdx.x, tid = threadIdx.x;

  const float* xr = x + ((size_t)t * B_ + b) * H_;
  xs[tid] = xr[tid];
  xs[tid + 256] = xr[tid + 256];
  if (t == 0) {
    hs[tid] = 0.f;
    hs[tid + 256] = 0.f;
  } else {
    hs[tid] = hmod[(size_t)b * H_ + tid];
    hs[tid + 256] = hmod[(size_t)b * H_ + tid + 256];
  }
  __syncthreads();

  // gates = [x, h] @ W^T + b
  for (int j = tid; j < 2048; j += 256) {
    const float* wr = W + (size_t)j * 1024;
    float a = 0.f;
    for (int k = 0; k < 512; ++k) a += xs[k] * wr[k];
    for (int k = 0; k < 512; ++k) a += hs[k] * wr[512 + k];
    gt[j] = a + bb[j];
  }
  __syncthreads();

  // per-gate LN + activation, torch order (i,f,g,o): tanh on chunk 2
  for (int G = 0; G < 4; ++G) {
    float v0 = gt[G * 512 + tid], v1 = gt[G * 512 + tid + 256];
    float mu = bsum(v0 + v1, red) * (1.f / 512.f);
    float d0 = v0 - mu, d1 = v1 - mu;
    float var = bsum(d0 * d0 + d1 * d1, red) * (1.f / 512.f);
    float rs = rsqrtf(var + 1e-5f);
    float z0 = d0 * rs * lg[G * 512 + tid] + lb[G * 512 + tid];
    float z1 = d1 * rs * lg[G * 512 + tid + 256] + lb[G * 512 + tid + 256];
    ac[G * 512 + tid] = (G == 2) ? tanhf(z0) : sig_(z0);
    ac[G * 512 + tid + 256] = (G == 2) ? tanhf(z1) : sig_(z1);
  }
  __syncthreads();

  const size_t rb = (size_t)b * H_;
  float co0 = (t == 0) ? 0.f : cbuf[rb + tid];
  float co1 = (t == 0) ? 0.f : cbuf[rb + tid + 256];
  float cn0 = ac[512 + tid] * co0 + ac[tid] * ac[1024 + tid];
  float cn1 = ac[512 + tid + 256] * co1 + ac[tid + 256] * ac[1024 + tid + 256];
  float hh0 = ac[1536 + tid] * tanhf(cn0);
  float hh1 = ac[1536 + tid + 256] * tanhf(cn1);
  cbuf[rb + tid] = cn0;
  cbuf[rb + tid + 256] = cn1;
  hbuf[rb + tid] = hh0;
  hbuf[rb + tid + 256] = hh1;

  // im = x_t @ Wm^T + bm
  float imA = bm[tid], imB = bm[tid + 256];
  const float* wm0 = Wm + (size_t)tid * 512;
  const float* wm1 = Wm + (size_t)(tid + 256) * 512;
  for (int k = 0; k < 512; ++k) {
    imA += xs[k] * wm0[k];
    imB += xs[k] * wm1[k];
  }
  imb[rb + tid] = imA;
  imb[rb + tid + 256] = imB;

  float na2 = bsum(imA * imA + imB * imB, red);
  float hn2 = bsum(hh0 * hh0 + hh1 * hh1, red);
  float dih = bsum(imA * hh0 + imB * hh1, red);
  if (tid == 0) {
    float na = fmaxf(sqrtf(na2), 1e-6f);
    float nc = fmaxf(sqrtf(hn2), 1e-6f);
    nab[b] = na;
    gcob[b] = sig_((dih / (na * nc) + 1.f) * 0.5f);
  }
}

// ---- k2: one block per batch row b ----
__global__ __launch_bounds__(256) void f_k2(
    const float* __restrict__ cbuf, const float* __restrict__ hbuf,
    const float* __restrict__ imb, const float* __restrict__ nab,
    const float* __restrict__ gcob, float* __restrict__ hmod,
    float* __restrict__ ys, int t) {
  __shared__ float S[512];
  __shared__ float red[256];
  const int b = blockIdx.x, tid = threadIdx.x;

  float s0 = 0.f, s1 = 0.f;
  for (int q = 0; q < B_; ++q) {
    s0 += cbuf[(size_t)q * H_ + tid];
    s1 += cbuf[(size_t)q * H_ + tid + 256];
  }
  S[tid] = s0;
  S[tid + 256] = s1;
  float sn2 = bsum(s0 * s0 + s1 * s1, red);
  float snorm = fmaxf(sqrtf(sn2) * (1.f / 128.f), 1e-6f);

  const size_t rb = (size_t)b * H_;
  float i0 = imb[rb + tid], i1 = imb[rb + tid + 256];
  float dis = bsum(i0 * S[tid] + i1 * S[tid + 256], red);
  float cosv = (dis * (1.f / 128.f)) / (nab[b] * snorm);
  float gic = sig_((cosv + 1.f) * 0.5f);
  float gsc = gic + gcob[b];

  float h0 = hbuf[rb + tid] * gsc;
  float h1 = hbuf[rb + tid + 256] * gsc;
  hmod[rb + tid] = h0;
  hmod[rb + tid + 256] = h1;
  float* yr = ys + ((size_t)t * B_ + b) * H_;
  yr[tid] = h0;                 // FLOAT32 output
  yr[tid + 256] = h1;
}

namespace w22 {
constexpr size_t CB = 0;
constexpr size_t SZ = (size_t)B_ * H_ * 4;
constexpr size_t HB = CB + SZ;
constexpr size_t IMB = HB + SZ;
constexpr size_t HM = IMB + SZ;
constexpr size_t NA = HM + SZ;
constexpr size_t GCO = NA + 4096;
constexpr size_t NEED = GCO + 4096;
}

extern "C" void kernel_launch(void* const* d_in, const int* in_sizes, int n_in,
                              void* d_out, int out_size, void* d_ws, size_t ws_size,
                              hipStream_t stream) {
  float* ys = (float*)d_out;
  long long ncap = (long long)out_size;
  if (ncap > 16777216LL) ncap = 16777216LL;

  if (n_in < 7 || ws_size < w22::NEED) {
    fill6f<<<2048, 256, 0, stream>>>(ys, ncap);
    return;
  }

  const float* x = (const float*)d_in[0];
  const float* W = (const float*)d_in[1];
  const float* bb = (const float*)d_in[2];
  const float* Wm = (const float*)d_in[3];
  const float* bm = (const float*)d_in[4];
  const float* lg = (const float*)d_in[5];
  const float* lb = (const float*)d_in[6];

  char* ws = (char*)d_ws;
  float* cbuf = (float*)(ws + w22::CB);
  float* hbuf = (float*)(ws + w22::HB);
  float* imb = (float*)(ws + w22::IMB);
  float* hmod = (float*)(ws + w22::HM);
  float* nab = (float*)(ws + w22::NA);
  float* gcob = (float*)(ws + w22::GCO);

  for (int t = 0; t < T_; ++t) {
    f_k1<<<B_, 256, 0, stream>>>(x, W, bb, Wm, bm, lg, lb, hmod,
                                 cbuf, hbuf, imb, nab, gcob, t);
    f_k2<<<B_, 256, 0, stream>>>(cbuf, hbuf, imb, nab, gcob, hmod, ys, t);
  }
}

// Round 23
// 16024.197 us; speedup vs baseline: 4.4656x; 4.4656x over previous
//
#include <hip/hip_runtime.h>

// R23: f32 optimized pipeline (validated math from R22, restructured):
//  - Wt/Wmt k-major transposes (once)
//  - im precomputed for all T*B rows (one tiled GEMM)
//  - per step: kg (h_mod prologue + gates GEMM, 128 blocks) + kc (LN/cell, 128 blocks)
//  - tail kg(t=T) writes ys[T-1]

constexpr int T_ = 256, B_ = 128, H_ = 512;

typedef __attribute__((ext_vector_type(4))) float v4f;

__device__ __forceinline__ float sig_(float x) { return 1.f / (1.f + expf(-x)); }

__device__ __forceinline__ float bsum(float v, float* red) {
  const int tid = threadIdx.x;
  red[tid] = v;
  __syncthreads();
  for (int s = 128; s > 0; s >>= 1) {
    if (tid < s) red[tid] += red[tid + s];
    __syncthreads();
  }
  float r = red[0];
  __syncthreads();
  return r;
}

__global__ void fill6f(float* __restrict__ o, long long n) {
  for (long long i = (long long)blockIdx.x * 256 + threadIdx.x; i < n;
       i += (long long)gridDim.x * 256)
    o[i] = 6.0f;
}

// Wt[k*2048+j] = W[j*1024+k]
__global__ void tr_w(const float* __restrict__ W, float* __restrict__ Wt) {
  int i = blockIdx.x * 256 + threadIdx.x;
  if (i < 2048 * 1024) {
    int k = i >> 11, j = i & 2047;
    Wt[i] = W[(size_t)j * 1024 + k];
  }
}
// Wmt[k*512+j] = Wm[j*512+k]
__global__ void tr_wm(const float* __restrict__ Wm, float* __restrict__ Wmt) {
  int i = blockIdx.x * 256 + threadIdx.x;
  if (i < 512 * 512) {
    int k = i >> 9, j = i & 511;
    Wmt[i] = Wm[j * 512 + k];
  }
}

// im[r][col] = x[r] . Wmt[:,col] + bm[col], all 32768 rows.
// grid 2048: rt=bid>>1 (32 rows), ct=bid&1 (256 cols)
__global__ __launch_bounds__(256) void kim(const float* __restrict__ x,
                                           const float* __restrict__ Wmt,
                                           const float* __restrict__ bm,
                                           float* __restrict__ im) {
  __shared__ float xs[32][512];
  const int rt = blockIdx.x >> 1, ct = blockIdx.x & 1, tid = threadIdx.x;
  const int r0 = rt * 32;
  for (int idx = tid; idx < 4096; idx += 256) {
    int rr = idx >> 7, cc = (idx & 127) * 4;
    *(v4f*)&xs[rr][cc] = *(const v4f*)(x + ((size_t)r0 + rr) * 512 + cc);
  }
  __syncthreads();
  const int col = ct * 256 + tid;
  float acc[32];
#pragma unroll
  for (int r = 0; r < 32; ++r) acc[r] = 0.f;
#pragma unroll 4
  for (int k = 0; k < 512; ++k) {
    float w = Wmt[(size_t)k * 512 + col];
#pragma unroll
    for (int r = 0; r < 32; ++r) acc[r] += xs[r][k] * w;
  }
  float bb = bm[col];
  for (int r = 0; r < 32; ++r)
    im[((size_t)r0 + r) * 512 + col] = acc[r] + bb;
}

// kg: prologue (h_mod(t-1) from cbuf/hbuf/gco/nab/im; ys[t-1]) + gates GEMM.
// grid 128: rt=bid>>3 (8 rows), ct=bid&7 (256 cols). t==T_: prologue only.
__global__ __launch_bounds__(256) void kg(
    const float* __restrict__ x,    // [T,B,512]
    const float* __restrict__ Wt,   // [1024,2048] k-major
    const float* __restrict__ im,   // [T*B,512]
    const float* __restrict__ cbuf, // [128,512]
    const float* __restrict__ hbuf, // [128,512]
    const float* __restrict__ nab,  // [128]
    const float* __restrict__ gco,  // [128]
    float* __restrict__ gbuf,       // [128,2048]
    float* __restrict__ ys,         // [T,B,512]
    int t) {
  __shared__ float xh[8][1024];   // [x | h_mod]
  __shared__ float S[512];
  __shared__ float red[256];
  __shared__ float red2[256];
  __shared__ float gsc_sh[8];
  __shared__ float snorm_sh;
  const int tid = threadIdx.x, bid = blockIdx.x;
  const int rt = bid >> 3, ct = bid & 7;
  const int r0 = rt * 8;

  if (t == 0) {
    for (int rr = 0; rr < 8; ++rr) {
      xh[rr][512 + tid] = 0.f;
      xh[rr][768 + tid] = 0.f;
    }
  } else {
    // S = sum_b cbuf[b]; snorm = max(||S||/128, eps)
    const int c = tid * 2;
    float s0 = 0.f, s1 = 0.f;
    for (int p = 0; p < B_; ++p) {
      s0 += cbuf[(size_t)p * 512 + c];
      s1 += cbuf[(size_t)p * 512 + c + 1];
    }
    S[c] = s0;
    S[c + 1] = s1;
    float sn2 = bsum(s0 * s0 + s1 * s1, red);
    if (tid == 0) snorm_sh = fmaxf(sqrtf(sn2) * (1.f / 128.f), 1e-6f);
    __syncthreads();
    // dots: 8 rows x 32 threads
    const int r = tid >> 5, q = tid & 31;
    const float* ir = im + ((size_t)(t - 1) * B_ + r0 + r) * 512;
    float d = 0.f;
#pragma unroll
    for (int j = 0; j < 16; ++j) d += ir[q * 16 + j] * S[q * 16 + j];
    red2[tid] = d;
    __syncthreads();
    if (tid < 8) {
      float dot = 0.f;
#pragma unroll
      for (int q2 = 0; q2 < 32; ++q2) dot += red2[tid * 32 + q2];
      float cosv = (dot * (1.f / 128.f)) / (nab[r0 + tid] * snorm_sh);
      gsc_sh[tid] = sig_((cosv + 1.f) * 0.5f) + gco[r0 + tid];
    }
    __syncthreads();
    for (int rr = 0; rr < 8; ++rr) {
      const float gsc = gsc_sh[rr];
      float h0 = hbuf[((size_t)r0 + rr) * 512 + tid] * gsc;
      float h1 = hbuf[((size_t)r0 + rr) * 512 + tid + 256] * gsc;
      xh[rr][512 + tid] = h0;
      xh[rr][768 + tid] = h1;
      if (ct == 0) {
        float* yr = ys + ((size_t)(t - 1) * B_ + r0 + rr) * 512;
        yr[tid] = h0;
        yr[tid + 256] = h1;
      }
    }
  }
  if (t >= T_) return;

  for (int rr = 0; rr < 8; ++rr) {
    xh[rr][tid] = x[((size_t)t * B_ + r0 + rr) * 512 + tid];
    xh[rr][tid + 256] = x[((size_t)t * B_ + r0 + rr) * 512 + tid + 256];
  }
  __syncthreads();

  const int col = ct * 256 + tid;
  float acc[8];
#pragma unroll
  for (int r = 0; r < 8; ++r) acc[r] = 0.f;
#pragma unroll 8
  for (int k = 0; k < 1024; ++k) {
    float w = Wt[(size_t)k * 2048 + col];
#pragma unroll
    for (int r = 0; r < 8; ++r) acc[r] += xh[r][k] * w;
  }
#pragma unroll
  for (int rr = 0; rr < 8; ++rr)
    gbuf[((size_t)r0 + rr) * 2048 + col] = acc[rr];
}

// kc: LN + activations + cell + na + gco. 128 blocks, 1 row each.
__global__ __launch_bounds__(256) void kc(
    const float* __restrict__ gbuf, const float* __restrict__ bb,
    const float* __restrict__ lg, const float* __restrict__ lb,
    const float* __restrict__ im,
    float* __restrict__ cbuf, float* __restrict__ hbuf,
    float* __restrict__ nab, float* __restrict__ gco, int t) {
  __shared__ float gt[2048];
  __shared__ float ac[2048];
  __shared__ float red[256];
  const int row = blockIdx.x, tid = threadIdx.x;

  for (int j = tid; j < 2048; j += 256) gt[j] = gbuf[(size_t)row * 2048 + j] + bb[j];
  __syncthreads();

  for (int G = 0; G < 4; ++G) {
    float v0 = gt[G * 512 + tid], v1 = gt[G * 512 + tid + 256];
    float mu = bsum(v0 + v1, red) * (1.f / 512.f);
    float d0 = v0 - mu, d1 = v1 - mu;
    float var = bsum(d0 * d0 + d1 * d1, red) * (1.f / 512.f);
    float rs = rsqrtf(var + 1e-5f);
    float z0 = d0 * rs * lg[G * 512 + tid] + lb[G * 512 + tid];
    float z1 = d1 * rs * lg[G * 512 + tid + 256] + lb[G * 512 + tid + 256];
    ac[G * 512 + tid] = (G == 2) ? tanhf(z0) : sig_(z0);
    ac[G * 512 + tid + 256] = (G == 2) ? tanhf(z1) : sig_(z1);
  }
  __syncthreads();

  const size_t rb = (size_t)row * 512;
  float co0 = (t == 0) ? 0.f : cbuf[rb + tid];
  float co1 = (t == 0) ? 0.f : cbuf[rb + tid + 256];
  float cn0 = ac[512 + tid] * co0 + ac[tid] * ac[1024 + tid];
  float cn1 = ac[512 + tid + 256] * co1 + ac[tid + 256] * ac[1024 + tid + 256];
  float hh0 = ac[1536 + tid] * tanhf(cn0);
  float hh1 = ac[1536 + tid + 256] * tanhf(cn1);
  cbuf[rb + tid] = cn0;
  cbuf[rb + tid + 256] = cn1;
  hbuf[rb + tid] = hh0;
  hbuf[rb + tid + 256] = hh1;

  const float* ir = im + ((size_t)t * B_ + row) * 512;
  float imA = ir[tid], imB = ir[tid + 256];
  float na2 = bsum(imA * imA + imB * imB, red);
  float hn2 = bsum(hh0 * hh0 + hh1 * hh1, red);
  float dih = bsum(imA * hh0 + imB * hh1, red);
  if (tid == 0) {
    float na = fmaxf(sqrtf(na2), 1e-6f);
    float nc = fmaxf(sqrtf(hn2), 1e-6f);
    nab[row] = na;
    gco[row] = sig_((dih / (na * nc) + 1.f) * 0.5f);
  }
}

namespace w23 {
constexpr size_t WT = 0;                                   // 8 MB
constexpr size_t WT_SZ = (size_t)1024 * 2048 * 4;
constexpr size_t IM = WT + WT_SZ;                          // 64 MB
constexpr size_t IM_SZ = (size_t)T_ * B_ * 512 * 4;
constexpr size_t G = IM + IM_SZ;                           // 1 MB
constexpr size_t G_SZ = (size_t)B_ * 2048 * 4;
constexpr size_t CB = G + G_SZ;
constexpr size_t HC_SZ = (size_t)B_ * 512 * 4;
constexpr size_t HB = CB + HC_SZ;
constexpr size_t NA = HB + HC_SZ;
constexpr size_t GCO = NA + 4096;
constexpr size_t WMT = GCO + 4096;                         // 1 MB
constexpr size_t WMT_SZ = (size_t)512 * 512 * 4;
constexpr size_t NEED = WMT + WMT_SZ + 1024;
}

extern "C" void kernel_launch(void* const* d_in, const int* in_sizes, int n_in,
                              void* d_out, int out_size, void* d_ws, size_t ws_size,
                              hipStream_t stream) {
  float* ys = (float*)d_out;
  long long ncap = (long long)out_size;
  if (ncap > 16777216LL) ncap = 16777216LL;

  if (n_in < 7 || ws_size < w23::NEED) {
    fill6f<<<2048, 256, 0, stream>>>(ys, ncap);
    return;
  }

  const float* x = (const float*)d_in[0];
  const float* W = (const float*)d_in[1];
  const float* bb = (const float*)d_in[2];
  const float* Wm = (const float*)d_in[3];
  const float* bm = (const float*)d_in[4];
  const float* lg = (const float*)d_in[5];
  const float* lb = (const float*)d_in[6];

  char* ws = (char*)d_ws;
  float* Wt = (float*)(ws + w23::WT);
  float* im = (float*)(ws + w23::IM);
  float* gbuf = (float*)(ws + w23::G);
  float* cbuf = (float*)(ws + w23::CB);
  float* hbuf = (float*)(ws + w23::HB);
  float* nab = (float*)(ws + w23::NA);
  float* gco = (float*)(ws + w23::GCO);
  float* Wmt = (float*)(ws + w23::WMT);

  tr_w<<<8192, 256, 0, stream>>>(W, Wt);
  tr_wm<<<1024, 256, 0, stream>>>(Wm, Wmt);
  kim<<<2048, 256, 0, stream>>>(x, Wmt, bm, im);

  for (int t = 0; t < T_; ++t) {
    kg<<<128, 256, 0, stream>>>(x, Wt, im, cbuf, hbuf, nab, gco, gbuf, ys, t);
    kc<<<128, 256, 0, stream>>>(gbuf, bb, lg, lb, im, cbuf, hbuf, nab, gco, t);
  }
  kg<<<128, 256, 0, stream>>>(x, Wt, im, cbuf, hbuf, nab, gco, gbuf, ys, T_);
}

// Round 24
// 14780.785 us; speedup vs baseline: 4.8412x; 1.0841x over previous
//
#include <hip/hip_runtime.h>

// R24: validated math; optimizations:
//  - xg = x@Wx^T precomputed for all T*B rows (bf16 store), per-step K 1024->512
//    (tiered on ws_size; falls back to K=1024 inline path)
//  - wave-shuffle block reductions (2 barriers instead of 9)
//  - kg: 128 blocks (8 rows x 256 cols), kc: 128 blocks (1 row)

constexpr int T_ = 256, B_ = 128;

typedef __attribute__((ext_vector_type(4))) float v4f;
typedef unsigned short u16;

__device__ __forceinline__ float sig_(float x) { return 1.f / (1.f + expf(-x)); }
__device__ __forceinline__ float bf2f(u16 u) { return __uint_as_float(((unsigned)u) << 16); }
__device__ __forceinline__ u16 f2bf(float f) {
  union { float f; unsigned u; } c;
  c.f = f;
  unsigned r = c.u + 0x7FFFu + ((c.u >> 16) & 1u);
  return (u16)(r >> 16);
}

__device__ __forceinline__ float bsumf(float v, float* red4) {
  int tid = threadIdx.x, w = tid >> 6, l = tid & 63;
#pragma unroll
  for (int m = 1; m < 64; m <<= 1) v += __shfl_xor(v, m, 64);
  if (l == 0) red4[w] = v;
  __syncthreads();
  float r = red4[0] + red4[1] + red4[2] + red4[3];
  __syncthreads();
  return r;
}
__device__ __forceinline__ void bsum2(float a, float b, float* red8, float& ra, float& rb) {
  int tid = threadIdx.x, w = tid >> 6, l = tid & 63;
#pragma unroll
  for (int m = 1; m < 64; m <<= 1) {
    a += __shfl_xor(a, m, 64);
    b += __shfl_xor(b, m, 64);
  }
  if (l == 0) { red8[w] = a; red8[4 + w] = b; }
  __syncthreads();
  ra = red8[0] + red8[1] + red8[2] + red8[3];
  rb = red8[4] + red8[5] + red8[6] + red8[7];
  __syncthreads();
}
__device__ __forceinline__ void bsum3(float a, float b, float c, float* red12,
                                      float& ra, float& rb, float& rc) {
  int tid = threadIdx.x, w = tid >> 6, l = tid & 63;
#pragma unroll
  for (int m = 1; m < 64; m <<= 1) {
    a += __shfl_xor(a, m, 64);
    b += __shfl_xor(b, m, 64);
    c += __shfl_xor(c, m, 64);
  }
  if (l == 0) { red12[w] = a; red12[4 + w] = b; red12[8 + w] = c; }
  __syncthreads();
  ra = red12[0] + red12[1] + red12[2] + red12[3];
  rb = red12[4] + red12[5] + red12[6] + red12[7];
  rc = red12[8] + red12[9] + red12[10] + red12[11];
  __syncthreads();
}

__global__ void fill6f(float* __restrict__ o, long long n) {
  for (long long i = (long long)blockIdx.x * 256 + threadIdx.x; i < n;
       i += (long long)gridDim.x * 256)
    o[i] = 6.0f;
}

// Wt[k*2048+j] = W[j*1024+k]
__global__ void tr_w(const float* __restrict__ W, float* __restrict__ Wt) {
  int i = blockIdx.x * 256 + threadIdx.x;
  if (i < 2048 * 1024) {
    int k = i >> 11, j = i & 2047;
    Wt[i] = W[(size_t)j * 1024 + k];
  }
}
__global__ void tr_wm(const float* __restrict__ Wm, float* __restrict__ Wmt) {
  int i = blockIdx.x * 256 + threadIdx.x;
  if (i < 512 * 512) {
    int k = i >> 9, j = i & 511;
    Wmt[i] = Wm[j * 512 + k];
  }
}

// im for all rows: grid 2048 (32 rows x 2 col-halves)
__global__ __launch_bounds__(256) void kim(const float* __restrict__ x,
                                           const float* __restrict__ Wmt,
                                           const float* __restrict__ bm,
                                           float* __restrict__ im) {
  __shared__ float xs[32][512];
  const int rt = blockIdx.x >> 1, ct = blockIdx.x & 1, tid = threadIdx.x;
  const int r0 = rt * 32;
  for (int idx = tid; idx < 4096; idx += 256) {
    int rr = idx >> 7, cc = (idx & 127) * 4;
    *(v4f*)&xs[rr][cc] = *(const v4f*)(x + ((size_t)r0 + rr) * 512 + cc);
  }
  __syncthreads();
  const int col = ct * 256 + tid;
  float acc[32];
#pragma unroll
  for (int r = 0; r < 32; ++r) acc[r] = 0.f;
#pragma unroll 4
  for (int k = 0; k < 512; ++k) {
    float w = Wmt[(size_t)k * 512 + col];
#pragma unroll
    for (int r = 0; r < 32; ++r) acc[r] += xs[r][k] * w;
  }
  float bb = bm[col];
  for (int r = 0; r < 32; ++r) im[((size_t)r0 + r) * 512 + col] = acc[r] + bb;
}

// xg = x @ Wx^T, bf16 store. grid 4096 (64 rows x 8 col-tiles)
__global__ __launch_bounds__(256) void kxg(const float* __restrict__ x,
                                           const float* __restrict__ Wt,
                                           u16* __restrict__ xg) {
  __shared__ float xs[64][512];  // 128 KB
  const int rt = blockIdx.x >> 3, ct = blockIdx.x & 7, tid = threadIdx.x;
  const size_t r0 = (size_t)rt * 64;
  for (int idx = tid; idx < 8192; idx += 256) {
    int rr = idx >> 7, cc = (idx & 127) * 4;
    *(v4f*)&xs[rr][cc] = *(const v4f*)(x + (r0 + rr) * 512 + cc);
  }
  __syncthreads();
  const int col = ct * 256 + tid;
  float acc[64];
#pragma unroll
  for (int r = 0; r < 64; ++r) acc[r] = 0.f;
#pragma unroll 2
  for (int k = 0; k < 512; ++k) {
    float w = Wt[(size_t)k * 2048 + col];
#pragma unroll
    for (int r = 0; r < 64; ++r) acc[r] += xs[r][k] * w;
  }
  for (int r = 0; r < 64; ++r) xg[(r0 + r) * 2048 + col] = f2bf(acc[r]);
}

// kg: h_mod(t-1) prologue + gates GEMM. grid 128 (16 rt x 8 ct).
// use_xg: K=512 h-half + xg add; else K=1024 inline.
__global__ __launch_bounds__(256) void kg(
    const float* __restrict__ x, const float* __restrict__ Wt,
    const u16* __restrict__ xg, const float* __restrict__ im,
    const float* __restrict__ cbuf, const float* __restrict__ hbuf,
    const float* __restrict__ nab, const float* __restrict__ gco,
    float* __restrict__ gbuf, float* __restrict__ ys, int t, int use_xg) {
  __shared__ float xh[8][1024];  // [x | h_mod] (xg path uses [512..1023] only)
  __shared__ float S[512];
  __shared__ float red[16];
  __shared__ float red2[256];
  __shared__ float gsc_sh[8];
  __shared__ float snorm_sh;
  const int tid = threadIdx.x, bid = blockIdx.x;
  const int rt = bid >> 3, ct = bid & 7;
  const int r0 = rt * 8;

  if (t == 0) {
    for (int rr = 0; rr < 8; ++rr) {
      xh[rr][512 + tid] = 0.f;
      xh[rr][768 + tid] = 0.f;
    }
  } else {
    const int c = tid * 2;
    float s0 = 0.f, s1 = 0.f;
    for (int p = 0; p < B_; ++p) {
      s0 += cbuf[(size_t)p * 512 + c];
      s1 += cbuf[(size_t)p * 512 + c + 1];
    }
    S[c] = s0;
    S[c + 1] = s1;
    float sn2 = bsumf(s0 * s0 + s1 * s1, red);
    if (tid == 0) snorm_sh = fmaxf(sqrtf(sn2) * (1.f / 128.f), 1e-6f);
    __syncthreads();
    const int r = tid >> 5, q = tid & 31;
    const float* ir = im + ((size_t)(t - 1) * B_ + r0 + r) * 512;
    float d = 0.f;
#pragma unroll
    for (int j = 0; j < 16; ++j) d += ir[q * 16 + j] * S[q * 16 + j];
    red2[tid] = d;
    __syncthreads();
    if (tid < 8) {
      float dot = 0.f;
#pragma unroll
      for (int q2 = 0; q2 < 32; ++q2) dot += red2[tid * 32 + q2];
      float cosv = (dot * (1.f / 128.f)) / (nab[r0 + tid] * snorm_sh);
      gsc_sh[tid] = sig_((cosv + 1.f) * 0.5f) + gco[r0 + tid];
    }
    __syncthreads();
    for (int rr = 0; rr < 8; ++rr) {
      const float gsc = gsc_sh[rr];
      float h0 = hbuf[((size_t)r0 + rr) * 512 + tid] * gsc;
      float h1 = hbuf[((size_t)r0 + rr) * 512 + tid + 256] * gsc;
      xh[rr][512 + tid] = h0;
      xh[rr][768 + tid] = h1;
      if (ct == 0) {
        float* yr = ys + ((size_t)(t - 1) * B_ + r0 + rr) * 512;
        yr[tid] = h0;
        yr[tid + 256] = h1;
      }
    }
  }
  if (t >= T_) return;

  if (!use_xg) {
    for (int rr = 0; rr < 8; ++rr) {
      xh[rr][tid] = x[((size_t)t * B_ + r0 + rr) * 512 + tid];
      xh[rr][tid + 256] = x[((size_t)t * B_ + r0 + rr) * 512 + tid + 256];
    }
  }
  __syncthreads();

  const int col = ct * 256 + tid;
  float acc[8];
#pragma unroll
  for (int r = 0; r < 8; ++r) acc[r] = 0.f;
  if (use_xg) {
#pragma unroll 4
    for (int k = 0; k < 512; ++k) {
      float w = Wt[(size_t)(512 + k) * 2048 + col];
#pragma unroll
      for (int r = 0; r < 8; ++r) acc[r] += xh[r][512 + k] * w;
    }
#pragma unroll
    for (int r = 0; r < 8; ++r)
      acc[r] += bf2f(xg[((size_t)t * B_ + r0 + r) * 2048 + col]);
  } else {
#pragma unroll 4
    for (int k = 0; k < 1024; ++k) {
      float w = Wt[(size_t)k * 2048 + col];
#pragma unroll
      for (int r = 0; r < 8; ++r) acc[r] += xh[r][k] * w;
    }
  }
#pragma unroll
  for (int rr = 0; rr < 8; ++rr)
    gbuf[((size_t)r0 + rr) * 2048 + col] = acc[rr];
}

// kc: LN + activations + cell + na + gco. 128 blocks, 1 row each.
__global__ __launch_bounds__(256) void kc(
    const float* __restrict__ gbuf, const float* __restrict__ bb,
    const float* __restrict__ lg, const float* __restrict__ lb,
    const float* __restrict__ im,
    float* __restrict__ cbuf, float* __restrict__ hbuf,
    float* __restrict__ nab, float* __restrict__ gco, int t) {
  __shared__ float gt[2048];
  __shared__ float ac[2048];
  __shared__ float red[16];
  const int row = blockIdx.x, tid = threadIdx.x;

  for (int j = tid; j < 2048; j += 256) gt[j] = gbuf[(size_t)row * 2048 + j] + bb[j];
  __syncthreads();

  for (int G = 0; G < 4; ++G) {
    float v0 = gt[G * 512 + tid], v1 = gt[G * 512 + tid + 256];
    float s, sq;
    bsum2(v0 + v1, v0 * v0 + v1 * v1, red, s, sq);
    float mu = s * (1.f / 512.f);
    float var = sq * (1.f / 512.f) - mu * mu;
    float rs = rsqrtf(var + 1e-5f);
    float z0 = (v0 - mu) * rs * lg[G * 512 + tid] + lb[G * 512 + tid];
    float z1 = (v1 - mu) * rs * lg[G * 512 + tid + 256] + lb[G * 512 + tid + 256];
    ac[G * 512 + tid] = (G == 2) ? tanhf(z0) : sig_(z0);
    ac[G * 512 + tid + 256] = (G == 2) ? tanhf(z1) : sig_(z1);
  }
  __syncthreads();

  const size_t rb = (size_t)row * 512;
  float co0 = (t == 0) ? 0.f : cbuf[rb + tid];
  float co1 = (t == 0) ? 0.f : cbuf[rb + tid + 256];
  float cn0 = ac[512 + tid] * co0 + ac[tid] * ac[1024 + tid];
  float cn1 = ac[512 + tid + 256] * co1 + ac[tid + 256] * ac[1024 + tid + 256];
  float hh0 = ac[1536 + tid] * tanhf(cn0);
  float hh1 = ac[1536 + tid + 256] * tanhf(cn1);
  cbuf[rb + tid] = cn0;
  cbuf[rb + tid + 256] = cn1;
  hbuf[rb + tid] = hh0;
  hbuf[rb + tid + 256] = hh1;

  const float* ir = im + ((size_t)t * B_ + row) * 512;
  float imA = ir[tid], imB = ir[tid + 256];
  float na2, hn2, dih;
  bsum3(imA * imA + imB * imB, hh0 * hh0 + hh1 * hh1, imA * hh0 + imB * hh1,
        red, na2, hn2, dih);
  if (tid == 0) {
    float na = fmaxf(sqrtf(na2), 1e-6f);
    float nc = fmaxf(sqrtf(hn2), 1e-6f);
    nab[row] = na;
    gco[row] = sig_((dih / (na * nc) + 1.f) * 0.5f);
  }
}

namespace w24 {
constexpr size_t WT = 0;
constexpr size_t WT_SZ = (size_t)1024 * 2048 * 4;                 // 8 MB
constexpr size_t IM = WT + WT_SZ;
constexpr size_t IM_SZ = (size_t)T_ * B_ * 512 * 4;               // 64 MB
constexpr size_t G = IM + IM_SZ;
constexpr size_t G_SZ = (size_t)B_ * 2048 * 4;                    // 1 MB
constexpr size_t CB = G + G_SZ;
constexpr size_t HC_SZ = (size_t)B_ * 512 * 4;
constexpr size_t HB = CB + HC_SZ;
constexpr size_t NA = HB + HC_SZ;
constexpr size_t GCO = NA + 4096;
constexpr size_t WMT = GCO + 4096;
constexpr size_t WMT_SZ = (size_t)512 * 512 * 4;                  // 1 MB
constexpr size_t BASE_END = WMT + WMT_SZ + 1024;
constexpr size_t XG = BASE_END;
constexpr size_t XG_SZ = (size_t)T_ * B_ * 2048 * 2;              // 128 MB
constexpr size_t NEED_XG = XG + XG_SZ + 1024;
}

extern "C" void kernel_launch(void* const* d_in, const int* in_sizes, int n_in,
                              void* d_out, int out_size, void* d_ws, size_t ws_size,
                              hipStream_t stream) {
  float* ys = (float*)d_out;
  long long ncap = (long long)out_size;
  if (ncap > 16777216LL) ncap = 16777216LL;

  if (n_in < 7 || ws_size < w24::BASE_END) {
    fill6f<<<2048, 256, 0, stream>>>(ys, ncap);
    return;
  }
  const int use_xg = (ws_size >= w24::NEED_XG) ? 1 : 0;

  const float* x = (const float*)d_in[0];
  const float* W = (const float*)d_in[1];
  const float* bb = (const float*)d_in[2];
  const float* Wm = (const float*)d_in[3];
  const float* bm = (const float*)d_in[4];
  const float* lg = (const float*)d_in[5];
  const float* lb = (const float*)d_in[6];

  char* ws = (char*)d_ws;
  float* Wt = (float*)(ws + w24::WT);
  float* im = (float*)(ws + w24::IM);
  float* gbuf = (float*)(ws + w24::G);
  float* cbuf = (float*)(ws + w24::CB);
  float* hbuf = (float*)(ws + w24::HB);
  float* nab = (float*)(ws + w24::NA);
  float* gco = (float*)(ws + w24::GCO);
  float* Wmt = (float*)(ws + w24::WMT);
  u16* xg = (u16*)(ws + w24::XG);

  tr_w<<<8192, 256, 0, stream>>>(W, Wt);
  tr_wm<<<1024, 256, 0, stream>>>(Wm, Wmt);
  kim<<<2048, 256, 0, stream>>>(x, Wmt, bm, im);
  if (use_xg) kxg<<<4096, 256, 0, stream>>>(x, Wt, xg);

  for (int t = 0; t < T_; ++t) {
    kg<<<128, 256, 0, stream>>>(x, Wt, xg, im, cbuf, hbuf, nab, gco, gbuf, ys, t, use_xg);
    kc<<<128, 256, 0, stream>>>(gbuf, bb, lg, lb, im, cbuf, hbuf, nab, gco, t);
  }
  kg<<<128, 256, 0, stream>>>(x, Wt, xg, im, cbuf, hbuf, nab, gco, gbuf, ys, T_, use_xg);
}

// Round 25
// 9996.601 us; speedup vs baseline: 7.1582x; 1.4786x over previous
//
#include <hip/hip_runtime.h>

// R25: latency-focused restructure (validated math):
//  - kS: per-step S/snorm in one tiny kernel (kills kg's redundant 8.4M loads)
//  - kg: K-split x4 (512 blocks, 2/CU), K=128 chains, partials gb4[4]
//  - kc: 512 threads, column-aligned gates, folds xg+bias+4 partials at load
//  - im stored bf16 (ws ~174 MB < observed >=202 MB)

constexpr int T_ = 256, B_ = 128;

typedef __attribute__((ext_vector_type(4))) float v4f;
typedef unsigned short u16;

__device__ __forceinline__ float sig_(float x) { return 1.f / (1.f + expf(-x)); }
__device__ __forceinline__ float bf2f(u16 u) { return __uint_as_float(((unsigned)u) << 16); }
__device__ __forceinline__ u16 f2bf(float f) {
  union { float f; unsigned u; } c;
  c.f = f;
  unsigned r = c.u + 0x7FFFu + ((c.u >> 16) & 1u);
  return (u16)(r >> 16);
}

__global__ void fill6f(float* __restrict__ o, long long n) {
  for (long long i = (long long)blockIdx.x * 256 + threadIdx.x; i < n;
       i += (long long)gridDim.x * 256)
    o[i] = 6.0f;
}

// Wt[k*2048+j] = W[j*1024+k]
__global__ void tr_w(const float* __restrict__ W, float* __restrict__ Wt) {
  int i = blockIdx.x * 256 + threadIdx.x;
  if (i < 2048 * 1024) {
    int k = i >> 11, j = i & 2047;
    Wt[i] = W[(size_t)j * 1024 + k];
  }
}
__global__ void tr_wm(const float* __restrict__ Wm, float* __restrict__ Wmt) {
  int i = blockIdx.x * 256 + threadIdx.x;
  if (i < 512 * 512) {
    int k = i >> 9, j = i & 511;
    Wmt[i] = Wm[j * 512 + k];
  }
}

// im (bf16) for all rows: grid 2048 (32 rows x 2 col-halves)
__global__ __launch_bounds__(256) void kim(const float* __restrict__ x,
                                           const float* __restrict__ Wmt,
                                           const float* __restrict__ bm,
                                           u16* __restrict__ im) {
  __shared__ float xs[32][512];
  const int rt = blockIdx.x >> 1, ct = blockIdx.x & 1, tid = threadIdx.x;
  const int r0 = rt * 32;
  for (int idx = tid; idx < 4096; idx += 256) {
    int rr = idx >> 7, cc = (idx & 127) * 4;
    *(v4f*)&xs[rr][cc] = *(const v4f*)(x + ((size_t)r0 + rr) * 512 + cc);
  }
  __syncthreads();
  const int col = ct * 256 + tid;
  float acc[32];
#pragma unroll
  for (int r = 0; r < 32; ++r) acc[r] = 0.f;
#pragma unroll 4
  for (int k = 0; k < 512; ++k) {
    float w = Wmt[(size_t)k * 512 + col];
#pragma unroll
    for (int r = 0; r < 32; ++r) acc[r] += xs[r][k] * w;
  }
  float bb = bm[col];
  for (int r = 0; r < 32; ++r) im[((size_t)r0 + r) * 512 + col] = f2bf(acc[r] + bb);
}

// xg = x @ Wx^T (bf16). grid 4096 (64 rows x 8 col-tiles)
__global__ __launch_bounds__(256) void kxg(const float* __restrict__ x,
                                           const float* __restrict__ Wt,
                                           u16* __restrict__ xg) {
  __shared__ float xs[64][512];
  const int rt = blockIdx.x >> 3, ct = blockIdx.x & 7, tid = threadIdx.x;
  const size_t r0 = (size_t)rt * 64;
  for (int idx = tid; idx < 8192; idx += 256) {
    int rr = idx >> 7, cc = (idx & 127) * 4;
    *(v4f*)&xs[rr][cc] = *(const v4f*)(x + (r0 + rr) * 512 + cc);
  }
  __syncthreads();
  const int col = ct * 256 + tid;
  float acc[64];
#pragma unroll
  for (int r = 0; r < 64; ++r) acc[r] = 0.f;
#pragma unroll 2
  for (int k = 0; k < 512; ++k) {
    float w = Wt[(size_t)k * 2048 + col];
#pragma unroll
    for (int r = 0; r < 64; ++r) acc[r] += xs[r][k] * w;
  }
  for (int r = 0; r < 64; ++r) xg[(r0 + r) * 2048 + col] = f2bf(acc[r]);
}

// kS: S[c] = sum_p cbuf[p][c]; Sb[512] = snorm. 1 block x 512 threads.
__global__ __launch_bounds__(512) void kS(const float* __restrict__ cbuf,
                                          float* __restrict__ Sb) {
  __shared__ float red[8];
  const int c = threadIdx.x;
  float s = 0.f;
#pragma unroll 8
  for (int p = 0; p < B_; ++p) s += cbuf[(size_t)p * 512 + c];
  Sb[c] = s;
  float v = s * s;
  const int w = c >> 6, l = c & 63;
#pragma unroll
  for (int m = 1; m < 64; m <<= 1) v += __shfl_xor(v, m, 64);
  if (l == 0) red[w] = v;
  __syncthreads();
  if (c == 0) {
    float sn2 = 0.f;
#pragma unroll
    for (int i = 0; i < 8; ++i) sn2 += red[i];
    Sb[512] = fmaxf(sqrtf(sn2) * (1.f / 128.f), 1e-6f);
  }
}

// kg: gsc + h_mod staging + h-GEMM partial (K=128 chunk).
// grid 512: rt=bid>>5 (16), ct=(bid>>2)&7 (8), ks=bid&3 (4).
__global__ __launch_bounds__(256) void kg(
    const float* __restrict__ Wt,   // [1024,2048] k-major
    const u16* __restrict__ im,     // [T*B,512] bf16
    const float* __restrict__ Sb,   // [513]
    const float* __restrict__ hbuf, // [128,512]
    const float* __restrict__ nab,  // [128]
    const float* __restrict__ gco,  // [128]
    float* __restrict__ gb4,        // [4,128,2048]
    float* __restrict__ ys,         // [T,B,512]
    int t) {
  __shared__ float hM[8][128];
  __shared__ float red2[256];
  __shared__ float gsc_sh[8];
  const int tid = threadIdx.x, bid = blockIdx.x;
  const int rt = bid >> 5, ct = (bid >> 2) & 7, ks = bid & 3;
  const int r0 = rt * 8, c0 = ct * 256, kofs = ks * 128;

  if (t == 0) {
    for (int idx = tid; idx < 1024; idx += 256)
      hM[idx >> 7][idx & 127] = 0.f;
  } else {
    const float snorm = Sb[512];
    const int r = tid >> 5, q = tid & 31;
    const u16* ir = im + ((size_t)(t - 1) * B_ + r0 + r) * 512;
    float d = 0.f;
#pragma unroll
    for (int j = 0; j < 16; ++j) d += bf2f(ir[q * 16 + j]) * Sb[q * 16 + j];
    red2[tid] = d;
    __syncthreads();
    if (tid < 8) {
      float dot = 0.f;
#pragma unroll
      for (int q2 = 0; q2 < 32; ++q2) dot += red2[tid * 32 + q2];
      float cosv = (dot * (1.f / 128.f)) / (nab[r0 + tid] * snorm);
      gsc_sh[tid] = sig_((cosv + 1.f) * 0.5f) + gco[r0 + tid];
    }
    __syncthreads();
    for (int idx = tid; idx < 1024; idx += 256) {
      int rr = idx >> 7, j = idx & 127;
      hM[rr][j] = hbuf[((size_t)r0 + rr) * 512 + kofs + j] * gsc_sh[rr];
    }
    if (ct == 0 && ks == 0) {
      for (int rr = 0; rr < 8; ++rr) {
        const float gsc = gsc_sh[rr];
        float* yr = ys + ((size_t)(t - 1) * B_ + r0 + rr) * 512;
        yr[tid] = hbuf[((size_t)r0 + rr) * 512 + tid] * gsc;
        yr[tid + 256] = hbuf[((size_t)r0 + rr) * 512 + tid + 256] * gsc;
      }
    }
  }
  if (t >= T_) return;
  __syncthreads();

  const int col = c0 + tid;
  float acc[8];
#pragma unroll
  for (int r = 0; r < 8; ++r) acc[r] = 0.f;
#pragma unroll 8
  for (int k = 0; k < 128; ++k) {
    float w = Wt[(size_t)(512 + kofs + k) * 2048 + col];
#pragma unroll
    for (int r = 0; r < 8; ++r) acc[r] += hM[r][k] * w;
  }
#pragma unroll
  for (int rr = 0; rr < 8; ++rr)
    gb4[((size_t)ks * B_ + r0 + rr) * 2048 + col] = acc[rr];
}

// kc: 128 blocks x 512 threads; thread c owns column c of all 4 gates.
__global__ __launch_bounds__(512) void kc(
    const float* __restrict__ gb4, const u16* __restrict__ xg,
    const float* __restrict__ bb,
    const float* __restrict__ lg, const float* __restrict__ lb,
    const u16* __restrict__ im,
    float* __restrict__ cbuf, float* __restrict__ hbuf,
    float* __restrict__ nab, float* __restrict__ gco, int t) {
  __shared__ float red[24];
  const int row = blockIdx.x, c = threadIdx.x;
  const int w = c >> 6, l = c & 63;

  float a4[4];
#pragma unroll
  for (int G = 0; G < 4; ++G) {
    const int gcol = G * 512 + c;
    float v = bf2f(xg[((size_t)t * B_ + row) * 2048 + gcol]) + bb[gcol];
#pragma unroll
    for (int ks = 0; ks < 4; ++ks)
      v += gb4[((size_t)ks * B_ + row) * 2048 + gcol];
    // LN stats over 512 threads
    float s = v, sq = v * v;
#pragma unroll
    for (int m = 1; m < 64; m <<= 1) {
      s += __shfl_xor(s, m, 64);
      sq += __shfl_xor(sq, m, 64);
    }
    if (l == 0) { red[w] = s; red[8 + w] = sq; }
    __syncthreads();
    float st = 0.f, sqt = 0.f;
#pragma unroll
    for (int i = 0; i < 8; ++i) { st += red[i]; sqt += red[8 + i]; }
    __syncthreads();
    float mu = st * (1.f / 512.f);
    float var = sqt * (1.f / 512.f) - mu * mu;
    float rs = rsqrtf(var + 1e-5f);
    float z = (v - mu) * rs * lg[gcol] + lb[gcol];
    a4[G] = (G == 2) ? tanhf(z) : sig_(z);
  }

  const size_t rb = (size_t)row * 512;
  float cprev = (t == 0) ? 0.f : cbuf[rb + c];
  float cn = a4[1] * cprev + a4[0] * a4[2];
  float hh = a4[3] * tanhf(cn);
  cbuf[rb + c] = cn;
  hbuf[rb + c] = hh;

  float imv = bf2f(im[((size_t)t * B_ + row) * 512 + c]);
  float na2 = imv * imv, hn2 = hh * hh, dih = imv * hh;
#pragma unroll
  for (int m = 1; m < 64; m <<= 1) {
    na2 += __shfl_xor(na2, m, 64);
    hn2 += __shfl_xor(hn2, m, 64);
    dih += __shfl_xor(dih, m, 64);
  }
  if (l == 0) { red[w] = na2; red[8 + w] = hn2; red[16 + w] = dih; }
  __syncthreads();
  if (c == 0) {
    float A = 0.f, Hh = 0.f, D = 0.f;
#pragma unroll
    for (int i = 0; i < 8; ++i) { A += red[i]; Hh += red[8 + i]; D += red[16 + i]; }
    float na = fmaxf(sqrtf(A), 1e-6f);
    float nc = fmaxf(sqrtf(Hh), 1e-6f);
    nab[row] = na;
    gco[row] = sig_((D / (na * nc) + 1.f) * 0.5f);
  }
}

namespace w25 {
constexpr size_t WT = 0;
constexpr size_t WT_SZ = (size_t)1024 * 2048 * 4;              // 8 MB
constexpr size_t IMB = WT + WT_SZ;
constexpr size_t IMB_SZ = (size_t)T_ * B_ * 512 * 2;           // 32 MB
constexpr size_t GB4 = IMB + IMB_SZ;
constexpr size_t GB4_SZ = (size_t)4 * B_ * 2048 * 4;           // 4 MB
constexpr size_t CB = GB4 + GB4_SZ;
constexpr size_t HC_SZ = (size_t)B_ * 512 * 4;
constexpr size_t HB = CB + HC_SZ;
constexpr size_t NA = HB + HC_SZ;
constexpr size_t GCO = NA + 4096;
constexpr size_t SB = GCO + 4096;
constexpr size_t WMT = SB + 4096;
constexpr size_t WMT_SZ = (size_t)512 * 512 * 4;               // 1 MB
constexpr size_t XG = WMT + WMT_SZ;
constexpr size_t XG_SZ = (size_t)T_ * B_ * 2048 * 2;           // 128 MB
constexpr size_t NEED = XG + XG_SZ + 1024;                     // ~174 MB
}

extern "C" void kernel_launch(void* const* d_in, const int* in_sizes, int n_in,
                              void* d_out, int out_size, void* d_ws, size_t ws_size,
                              hipStream_t stream) {
  float* ys = (float*)d_out;
  long long ncap = (long long)out_size;
  if (ncap > 16777216LL) ncap = 16777216LL;

  if (n_in < 7 || ws_size < w25::NEED) {
    fill6f<<<2048, 256, 0, stream>>>(ys, ncap);
    return;
  }

  const float* x = (const float*)d_in[0];
  const float* W = (const float*)d_in[1];
  const float* bb = (const float*)d_in[2];
  const float* Wm = (const float*)d_in[3];
  const float* bm = (const float*)d_in[4];
  const float* lg = (const float*)d_in[5];
  const float* lb = (const float*)d_in[6];

  char* ws = (char*)d_ws;
  float* Wt = (float*)(ws + w25::WT);
  u16* im = (u16*)(ws + w25::IMB);
  float* gb4 = (float*)(ws + w25::GB4);
  float* cbuf = (float*)(ws + w25::CB);
  float* hbuf = (float*)(ws + w25::HB);
  float* nab = (float*)(ws + w25::NA);
  float* gco = (float*)(ws + w25::GCO);
  float* Sb = (float*)(ws + w25::SB);
  float* Wmt = (float*)(ws + w25::WMT);
  u16* xg = (u16*)(ws + w25::XG);

  tr_w<<<8192, 256, 0, stream>>>(W, Wt);
  tr_wm<<<1024, 256, 0, stream>>>(Wm, Wmt);
  kim<<<2048, 256, 0, stream>>>(x, Wmt, bm, im);
  kxg<<<4096, 256, 0, stream>>>(x, Wt, xg);

  for (int t = 0; t < T_; ++t) {
    kg<<<512, 256, 0, stream>>>(Wt, im, Sb, hbuf, nab, gco, gb4, ys, t);
    kc<<<128, 512, 0, stream>>>(gb4, xg, bb, lg, lb, im, cbuf, hbuf, nab, gco, t);
    kS<<<1, 512, 0, stream>>>(cbuf, Sb);
  }
  kg<<<512, 256, 0, stream>>>(Wt, im, Sb, hbuf, nab, gco, gb4, ys, T_);
}